// Round 6
// baseline (245.693 us; speedup 1.0000x reference)
//
#include <hip/hip_runtime.h>
#include <hip/hip_bf16.h>
#include <stdint.h>

typedef __hip_bfloat16 bf16;
typedef __attribute__((ext_vector_type(8))) short short8;
typedef __attribute__((ext_vector_type(4))) float float4v;
typedef __attribute__((ext_vector_type(2))) float f2v;

#define NVOCAB 113
#define NPAIR (113 * 113)   // 12769
#define DDIM 128
#define HIDDIM 512
#define PAIRS_PB 16         // pairs per block
#define ROWS_PB 32          // rows per block

// fp32 pool element offsets (only biases used)
#define OFF_B1  145792
#define OFF_B2  211840

// bf16 transposed weight pool wb (element offsets)
#define BOFF_WOT 0                         // WOT[d][hk] = W_O[hk][d]     128x128
#define BOFF_W1T 16384                     // W1T[n][d]  = W1[d][n]       512x128
#define BOFF_W2T (16384 + 65536)           // W2T[d][j]  = W2[j][d]       128x512
#define BOFF_WUP (16384 + 65536 + 65536)   // WUP[v][d]  = W_U[v][d]|0    128x128
#define BTOTAL   (16384 + 65536 + 65536 + 16384)  // 163840

__device__ __forceinline__ uint16_t f2b(float f) {
  bf16 h = __float2bfloat16(f);
  return *(uint16_t*)&h;
}
__device__ __forceinline__ float b2f(uint16_t u) {
  return __uint_as_float(((uint32_t)u) << 16);
}
__device__ __forceinline__ float ldsrc(const void* p, int i, int isb) {
  return isb ? b2f(((const uint16_t*)p)[i]) : ((const float*)p)[i];
}

// per-wave dtype self-detection: 64 samples of tok_emb raw u32s.
// bf16 data: low-half exponent in [100,126] for ~all samples; fp32 data:
// those bits are mantissa noise (~10% hit rate). Threshold 48/64.
__device__ __forceinline__ int detect_isb(const uint32_t* __restrict__ tok_raw) {
  uint32_t u = tok_raw[threadIdx.x & 63];
  int e = (u >> 7) & 0xff;
  unsigned long long m = __ballot(e >= 100 && e <= 126);
  return __popcll(m) >= 48;
}

struct SrcPtrs { const void* p[11]; };
// p[0]=tok p[1]=pos p[2]=WQ p[3]=WK p[4]=WV p[5]=WO p[6]=W1 p[7]=b1 p[8]=W2 p[9]=b2 p[10]=WU

// ---------------- K1: all prep in one launch, sources read directly --------
// blocks [0,226)   : qkv + resid_pre
// blocks [226,653) : wb transposed bf16 weights
// blocks [653,655) : bias convert into wf pool
__global__ void __launch_bounds__(384) build_kernel(
    SrcPtrs sp, float* __restrict__ wf,
    float* __restrict__ resid_pre, float* __restrict__ qt,
    float* __restrict__ kt, float* __restrict__ vt,
    uint16_t* __restrict__ wb) {
  const int tid = threadIdx.x;
  const int blk = blockIdx.x;
  const int isb = detect_isb((const uint32_t*)sp.p[0]);

  if (blk < 226) {
    // ---- qkv + resid ----
    const int row = blk;
    const int t = row >> 1, p = row & 1;
    __shared__ float r[DDIM];
    if (tid < DDIM) {
      float rv = ldsrc(sp.p[0], t * DDIM + tid, isb) +
                 ldsrc(sp.p[1], p * DDIM + tid, isb);
      r[tid] = rv;
      resid_pre[row * DDIM + tid] = rv;
    }
    __syncthreads();
    const int which = tid >> 7, jj = tid & 127;
    const int h = jj >> 5, j = jj & 31;
    const void* wsrc = sp.p[2 + which];
    const int base = h * 4096 + j;
    float a = 0.f;
    if (isb) {
      const uint16_t* w16 = (const uint16_t*)wsrc;
      #pragma unroll 8
      for (int d = 0; d < 128; ++d)
        a += r[d] * b2f(w16[base + d * 32]);
    } else {
      const float* w32 = (const float*)wsrc;
      #pragma unroll 8
      for (int d = 0; d < 128; ++d)
        a += r[d] * w32[base + d * 32];
    }
    float* outp = (which == 0) ? qt : (which == 1) ? kt : vt;
    outp[row * DDIM + jj] = a;
  } else if (blk < 653) {
    // ---- wb build ----
    const int idx = (blk - 226) * 384 + tid;
    if (idx < BTOTAL) {
      float v;
      if (idx < BOFF_W1T) {                       // WOT[d][c] = W_O[c*128+d]
        int l = idx, d = l >> 7, c = l & 127;
        v = ldsrc(sp.p[5], c * 128 + d, isb);
      } else if (idx < BOFF_W2T) {                // W1T[n][d] = W1[d*512+n]
        int l = idx - BOFF_W1T, n = l >> 7, d = l & 127;
        v = ldsrc(sp.p[6], d * 512 + n, isb);
      } else if (idx < BOFF_WUP) {                // W2T[d][j] = W2[j*128+d]
        int l = idx - BOFF_W2T, d = l >> 9, j = l & 511;
        v = ldsrc(sp.p[8], j * 128 + d, isb);
      } else {                                    // WUP[v][d] = W_U[v*128+d] or 0
        int l = idx - BOFF_WUP, vv = l >> 7, d = l & 127;
        v = (vv < NVOCAB) ? ldsrc(sp.p[10], vv * 128 + d, isb) : 0.f;
      }
      wb[idx] = f2b(v);
    }
  } else {
    // ---- biases ----
    const int i = (blk - 653) * 384 + tid;
    if (i < 512) wf[OFF_B1 + i] = ldsrc(sp.p[7], i, isb);
    else if (i < 640) wf[OFF_B2 + (i - 512)] = ldsrc(sp.p[9], i - 512, isb);
  }
}

// ---------------- K2: fused MFMA kernel, 16 pairs (32 rows) / block -------
// R4 compute core (identical MFMA order); GEMM3 stores DENSE into the
// 11.5 MB table (L2-resident) instead of scatter-writing 118 MB to out.
__global__ void __launch_bounds__(512, 3) pair_mfma_kernel(
    const float* __restrict__ resid_pre, const float* __restrict__ qt,
    const float* __restrict__ kt, const float* __restrict__ vt,
    const float* __restrict__ wf, const uint16_t* __restrict__ wb,
    float* __restrict__ table) {
  __shared__ uint16_t bufH[ROWS_PB * 512];   // 32 KB (H staging)
  __shared__ uint16_t bufZ[ROWS_PB * 128];   // 8 KB (Z, then R)
  __shared__ uint16_t bufS[ROWS_PB * 128];   // 8 KB (smid bf16)
  __shared__ float    spat[PAIRS_PB * 16];

  const int tid = threadIdx.x;
  const int blk = blockIdx.x;
  const int lane = tid & 63;
  const int npar = tid >> 6;            // wave id 0..7
  const int l15 = lane & 15, quad = lane >> 4;

  #define ROW_OF(row_) ({                                        \
    int pr_ = blk * PAIRS_PB + ((row_) >> 1);                    \
    if (pr_ >= NPAIR) pr_ = NPAIR - 1;                           \
    int t0_ = pr_ / NVOCAB, t1_ = pr_ - t0_ * NVOCAB;            \
    ((row_) & 1) ? t1_ * 2 + 1 : t0_ * 2; })

  // ---- top-of-kernel prefetches (ride the prologue latency) ----
  const int nG = npar * 16 + l15;       // N=128 column for GEMM0/2/3
  float rpre[2][4];
  #pragma unroll
  for (int mf = 0; mf < 2; ++mf)
    #pragma unroll
    for (int r = 0; r < 4; ++r)
      rpre[mf][r] = resid_pre[ROW_OF(mf * 16 + quad * 4 + r) * DDIM + nG];
  float bias1v[4];
  #pragma unroll
  for (int ni = 0; ni < 4; ++ni)
    bias1v[ni] = wf[OFF_B1 + (npar + ni * 8) * 16 + l15];
  const float bias2 = wf[OFF_B2 + nG];
  // vt rows for the Z phase: 2 rows x 8 cols
  const int zm = tid >> 4, zc0 = (tid & 15) * 8;
  float4 zv0a, zv0b, zv1a, zv1b;
  {
    const int zr0 = ROW_OF((zm >> 1) * 2);
    const int zr1 = ROW_OF((zm >> 1) * 2 + 1);
    const float4* p0 = (const float4*)(vt + zr0 * DDIM + zc0);
    const float4* p1 = (const float4*)(vt + zr1 * DDIM + zc0);
    zv0a = p0[0]; zv0b = p0[1]; zv1a = p1[0]; zv1b = p1[1];
  }

  // ---- prologue: scores (16 pairs x 16 scores = 256 threads) ----
  if (tid < 256) {
    const int pl = tid >> 4, s = tid & 15;
    const int pair = blk * PAIRS_PB + pl;
    if (pair < NPAIR) {
      const int t0 = pair / NVOCAB, t1 = pair - t0 * NVOCAB;
      const int row0 = t0 * 2, row1 = t1 * 2 + 1;
      const int h = s >> 2, qp = (s >> 1) & 1, spp = s & 1;
      const float4* qrow = (const float4*)(qt + (qp ? row1 : row0) * DDIM + h * 32);
      const float4* krow = (const float4*)(kt + (spp ? row1 : row0) * DDIM + h * 32);
      float acc = 0.f;
      #pragma unroll
      for (int j = 0; j < 8; ++j) {
        float4 qv = qrow[j], kv = krow[j];
        acc += qv.x * kv.x + qv.y * kv.y + qv.z * kv.z + qv.w * kv.w;
      }
      spat[pl * 16 + s] = acc * 0.17677669529663687f;
    } else {
      spat[pl * 16 + s] = 0.f;
    }
  }
  __syncthreads();

  // ---- softmax + blend ----
  if (tid < 128) {
    const int pl = tid >> 3, s = tid & 7;
    const int base = pl * 16 + s * 2;
    float s0 = spat[base], s1 = spat[base + 1];
    float m = fmaxf(s0, s1);
    float e0 = __expf(s0 - m), e1 = __expf(s1 - m);
    float inv = 1.f / (e0 + e1);
    spat[base]     = 0.5f + 0.5f * e0 * inv;
    spat[base + 1] = 0.5f + 0.5f * e1 * inv;
  }
  __syncthreads();

  // ---- Z = pattern-weighted V (prefetched), staged bf16 ----
  {
    const int pl = zm >> 1, qp = zm & 1;
    const int h = zc0 >> 5;
    const float p0 = spat[pl * 16 + h * 4 + qp * 2];
    const float p1 = spat[pl * 16 + h * 4 + qp * 2 + 1];
    float v0[8] = {zv0a.x, zv0a.y, zv0a.z, zv0a.w, zv0b.x, zv0b.y, zv0b.z, zv0b.w};
    float v1[8] = {zv1a.x, zv1a.y, zv1a.z, zv1a.w, zv1b.x, zv1b.y, zv1b.z, zv1b.w};
    short8 pk;
    #pragma unroll
    for (int e = 0; e < 8; ++e)
      pk[e] = (short)f2b(p0 * v0[e] + p1 * v1[e]);
    *(short8*)&bufZ[(zm * 16 + ((zc0 >> 3) ^ (zm & 15))) * 8] = pk;
  }
  __syncthreads();

  float smid[2][4];

  // ---- GEMM0: smid = Z x WOT + resid  (N=128, K=128) ----
  {
    short8 af[2][4];
    #pragma unroll
    for (int mf = 0; mf < 2; ++mf)
      #pragma unroll
      for (int ks = 0; ks < 4; ++ks)
        af[mf][ks] = *(const short8*)&bufZ[((mf * 16 + l15) * 16 +
                                           ((ks * 4 + quad) ^ l15)) * 8];
    short8 bW[4];
    {
      const uint16_t* bp = wb + BOFF_WOT + nG * 128 + quad * 8;
      #pragma unroll
      for (int ks = 0; ks < 4; ++ks)
        bW[ks] = *(const short8*)(bp + ks * 32);
    }
    float4v acc[2] = {{0.f, 0.f, 0.f, 0.f}, {0.f, 0.f, 0.f, 0.f}};
    #pragma unroll
    for (int mf = 0; mf < 2; ++mf)
      #pragma unroll
      for (int ks = 0; ks < 4; ++ks)
        acc[mf] = __builtin_amdgcn_mfma_f32_16x16x32_bf16(af[mf][ks], bW[ks],
                                                          acc[mf], 0, 0, 0);
    #pragma unroll
    for (int mf = 0; mf < 2; ++mf)
      #pragma unroll
      for (int r = 0; r < 4; ++r) {
        const int row = mf * 16 + quad * 4 + r;
        float v = acc[mf][r] + rpre[mf][r];
        smid[mf][r] = v;
        bufS[(row * 16 + ((nG >> 3) ^ (row & 15))) * 8 + (nG & 7)] = f2b(v);
      }
  }
  __syncthreads();

  // ---- GEMM1: H = relu(smid x W1 + b1)  (N=512, K=128) ----
  {
    short8 af[2][4];
    #pragma unroll
    for (int mf = 0; mf < 2; ++mf)
      #pragma unroll
      for (int ks = 0; ks < 4; ++ks)
        af[mf][ks] = *(const short8*)&bufS[((mf * 16 + l15) * 16 +
                                           ((ks * 4 + quad) ^ l15)) * 8];
    #pragma unroll
    for (int half = 0; half < 2; ++half) {
      short8 bW[2][4];
      #pragma unroll
      for (int nj = 0; nj < 2; ++nj) {
        const int ni = half * 2 + nj;
        const int n = (npar + ni * 8) * 16 + l15;
        const uint16_t* bp = wb + BOFF_W1T + n * 128 + quad * 8;
        #pragma unroll
        for (int ks = 0; ks < 4; ++ks)
          bW[nj][ks] = *(const short8*)(bp + ks * 32);
      }
      #pragma unroll
      for (int nj = 0; nj < 2; ++nj) {
        const int ni = half * 2 + nj;
        const int n = (npar + ni * 8) * 16 + l15;
        float4v acc[2] = {{0.f, 0.f, 0.f, 0.f}, {0.f, 0.f, 0.f, 0.f}};
        #pragma unroll
        for (int mf = 0; mf < 2; ++mf)
          #pragma unroll
          for (int ks = 0; ks < 4; ++ks)
            acc[mf] = __builtin_amdgcn_mfma_f32_16x16x32_bf16(
                af[mf][ks], bW[nj][ks], acc[mf], 0, 0, 0);
        const float bias = bias1v[ni];
        #pragma unroll
        for (int mf = 0; mf < 2; ++mf)
          #pragma unroll
          for (int r = 0; r < 4; ++r) {
            const int row = mf * 16 + quad * 4 + r;
            bufH[(row * 64 + ((n >> 3) ^ (row & 15))) * 8 + (n & 7)] =
                f2b(fmaxf(acc[mf][r] + bias, 0.f));
          }
      }
    }
  }
  __syncthreads();

  // ---- GEMM2: R = smid + H x W2 + b2  (N=128, K=512) ----
  {
    const uint16_t* bp = wb + BOFF_W2T + nG * 512 + quad * 8;
    float4v acc0 = {0.f, 0.f, 0.f, 0.f};
    float4v acc1 = {0.f, 0.f, 0.f, 0.f};
    #pragma unroll
    for (int half = 0; half < 2; ++half) {
      short8 bB[8];
      #pragma unroll
      for (int k8 = 0; k8 < 8; ++k8)
        bB[k8] = *(const short8*)(bp + (half * 8 + k8) * 32);
      #pragma unroll
      for (int qtr = 0; qtr < 2; ++qtr) {
        short8 a0[4], a1[4];
        #pragma unroll
        for (int k4 = 0; k4 < 4; ++k4) {
          const int ks = half * 8 + qtr * 4 + k4;
          a0[k4] = *(const short8*)&bufH[(l15 * 64 +
                                         ((ks * 4 + quad) ^ l15)) * 8];
          a1[k4] = *(const short8*)&bufH[((16 + l15) * 64 +
                                         ((ks * 4 + quad) ^ l15)) * 8];
        }
        #pragma unroll
        for (int k4 = 0; k4 < 4; ++k4) {
          acc0 = __builtin_amdgcn_mfma_f32_16x16x32_bf16(
              a0[k4], bB[qtr * 4 + k4], acc0, 0, 0, 0);
          acc1 = __builtin_amdgcn_mfma_f32_16x16x32_bf16(
              a1[k4], bB[qtr * 4 + k4], acc1, 0, 0, 0);
        }
      }
    }
    #pragma unroll
    for (int r = 0; r < 4; ++r) {
      const int row0 = quad * 4 + r;
      const int row1 = 16 + quad * 4 + r;
      bufZ[(row0 * 16 + ((nG >> 3) ^ (row0 & 15))) * 8 + (nG & 7)] =
          f2b(acc0[r] + bias2 + smid[0][r]);
      bufZ[(row1 * 16 + ((nG >> 3) ^ (row1 & 15))) * 8 + (nG & 7)] =
          f2b(acc1[r] + bias2 + smid[1][r]);
    }
  }
  __syncthreads();

  // ---- GEMM3: logits = R x WUP^T -> DENSE table store (L2-resident) ----
  {
    short8 ar[2][4];
    #pragma unroll
    for (int mf = 0; mf < 2; ++mf)
      #pragma unroll
      for (int ks = 0; ks < 4; ++ks)
        ar[mf][ks] = *(const short8*)&bufZ[((mf * 16 + l15) * 16 +
                                           ((ks * 4 + quad) ^ l15)) * 8];
    short8 bW[4];
    {
      const uint16_t* bp = wb + BOFF_WUP + nG * 128 + quad * 8;
      #pragma unroll
      for (int ks = 0; ks < 4; ++ks)
        bW[ks] = *(const short8*)(bp + ks * 32);
    }
    float4v acc[2] = {{0.f, 0.f, 0.f, 0.f}, {0.f, 0.f, 0.f, 0.f}};
    #pragma unroll
    for (int mf = 0; mf < 2; ++mf)
      #pragma unroll
      for (int ks = 0; ks < 4; ++ks)
        acc[mf] = __builtin_amdgcn_mfma_f32_16x16x32_bf16(ar[mf][ks], bW[ks],
                                                          acc[mf], 0, 0, 0);
    if (nG < NVOCAB) {
      #pragma unroll
      for (int mf = 0; mf < 2; ++mf)
        #pragma unroll
        for (int r = 0; r < 4; ++r) {
          const int row = mf * 16 + quad * 4 + r;
          const int pair = blk * PAIRS_PB + (row >> 1);
          if (pair < NPAIR)
            table[pair * 226 + (row & 1) * 113 + nG] = acc[mf][r];
        }
    }
  }
  #undef ROW_OF
}

// ---------------- K3: gather — random L2 table reads, DENSE out writes -----
__global__ void gather_kernel(const uint32_t* __restrict__ x_raw,
                              const f2v* __restrict__ table2,
                              f2v* __restrict__ out2, int total) {
  // per-wave int64 self-detect: int64 tokens -> odd u32s (high words) all 0
  uint32_t xs = x_raw[2 * (threadIdx.x & 63) + 1];
  unsigned long long nz = __ballot(xs != 0u);
  const int is64 = (nz == 0ull);

  const int i = blockIdx.x * 256 + threadIdx.x;
  if (i >= total) return;
  const int b = i / NVOCAB;
  const int j = i - b * NVOCAB;
  int t0, t1;
  if (is64) {
    t0 = (int)x_raw[4 * b];
    t1 = (int)x_raw[4 * b + 2];
  } else {
    t0 = (int)x_raw[2 * b];
    t1 = (int)x_raw[2 * b + 1];
  }
  t0 = min(max(t0, 0), NVOCAB - 1);
  t1 = min(max(t1, 0), NVOCAB - 1);
  const int pair = t0 * NVOCAB + t1;
  f2v v = table2[(size_t)pair * NVOCAB + j];
  __builtin_nontemporal_store(v, &out2[i]);
}

extern "C" void kernel_launch(void* const* d_in, const int* in_sizes, int n_in,
                              void* d_out, int out_size, void* d_ws, size_t ws_size,
                              hipStream_t stream) {
  // ws layout (byte offsets)
  float*    wf        = (float*)((char*)d_ws + 256);             // biases only
  float*    resid_pre = (float*)((char*)d_ws + 905984);
  float*    qt        = (float*)((char*)d_ws + 1021696);
  float*    kt        = (float*)((char*)d_ws + 1137408);
  float*    vt        = (float*)((char*)d_ws + 1253120);
  float*    table     = (float*)((char*)d_ws + 1368832);         // 11543176 B
  uint16_t* wb        = (uint16_t*)((char*)d_ws + 12912016);     // 327680 B

  const int B = in_sizes[0] / 2;

  SrcPtrs sp;
  for (int i = 0; i < 11; ++i) sp.p[i] = d_in[i + 1];

  // 226 qkv + 427 wb + 2 bias = 655 blocks
  build_kernel<<<655, 384, 0, stream>>>(sp, wf, resid_pre, qt, kt, vt, wb);

  const int nblk = (NPAIR + PAIRS_PB - 1) / PAIRS_PB;  // 799
  pair_mfma_kernel<<<nblk, 512, 0, stream>>>(resid_pre, qt, kt, vt, wf, wb,
                                             table);

  const int total = B * NVOCAB;   // float2 elements of out
  gather_kernel<<<(total + 255) / 256, 256, 0, stream>>>(
      (const uint32_t*)d_in[0], (const f2v*)table, (f2v*)d_out, total);
}

// Round 7
// 242.664 us; speedup vs baseline: 1.0125x; 1.0125x over previous
//
#include <hip/hip_runtime.h>
#include <hip/hip_bf16.h>
#include <stdint.h>

typedef __hip_bfloat16 bf16;
typedef __attribute__((ext_vector_type(8))) short short8;
typedef __attribute__((ext_vector_type(4))) float float4v;
typedef __attribute__((ext_vector_type(2))) float f2v;

#define NVOCAB 113
#define NPAIR (113 * 113)   // 12769
#define DDIM 128
#define HIDDIM 512
#define PAIRS_PB 16         // pairs per block
#define ROWS_PB 32          // rows per block

// fp32 pool element offsets (only biases used)
#define OFF_B1  145792
#define OFF_B2  211840

// bf16 transposed weight pool wb (element offsets)
#define BOFF_WOT 0                         // WOT[d][hk] = W_O[hk][d]     128x128
#define BOFF_W1T 16384                     // W1T[n][d]  = W1[d][n]       512x128
#define BOFF_W2T (16384 + 65536)           // W2T[d][j]  = W2[j][d]       128x512
#define BOFF_WUP (16384 + 65536 + 65536)   // WUP[v][d]  = W_U[v][d]|0    128x128
#define BTOTAL   (16384 + 65536 + 65536 + 16384)  // 163840

__device__ __forceinline__ uint16_t f2b(float f) {
  bf16 h = __float2bfloat16(f);
  return *(uint16_t*)&h;
}
__device__ __forceinline__ float b2f(uint16_t u) {
  return __uint_as_float(((uint32_t)u) << 16);
}
__device__ __forceinline__ float ldsrc(const void* p, int i, int isb) {
  return isb ? b2f(((const uint16_t*)p)[i]) : ((const float*)p)[i];
}

// per-wave dtype self-detection: 64 samples of tok_emb raw u32s.
__device__ __forceinline__ int detect_isb(const uint32_t* __restrict__ tok_raw) {
  uint32_t u = tok_raw[threadIdx.x & 63];
  int e = (u >> 7) & 0xff;
  unsigned long long m = __ballot(e >= 100 && e <= 126);
  return __popcll(m) >= 48;
}

struct SrcPtrs { const void* p[11]; };
// p[0]=tok p[1]=pos p[2]=WQ p[3]=WK p[4]=WV p[5]=WO p[6]=W1 p[7]=b1 p[8]=W2 p[9]=b2 p[10]=WU

// ---------------- K1: all prep in one launch, sources read directly --------
__global__ void __launch_bounds__(384) build_kernel(
    SrcPtrs sp, float* __restrict__ wf,
    float* __restrict__ resid_pre, float* __restrict__ qt,
    float* __restrict__ kt, float* __restrict__ vt,
    uint16_t* __restrict__ wb) {
  const int tid = threadIdx.x;
  const int blk = blockIdx.x;
  const int isb = detect_isb((const uint32_t*)sp.p[0]);

  if (blk < 226) {
    // ---- qkv + resid ----
    const int row = blk;
    const int t = row >> 1, p = row & 1;
    __shared__ float r[DDIM];
    if (tid < DDIM) {
      float rv = ldsrc(sp.p[0], t * DDIM + tid, isb) +
                 ldsrc(sp.p[1], p * DDIM + tid, isb);
      r[tid] = rv;
      resid_pre[row * DDIM + tid] = rv;
    }
    __syncthreads();
    const int which = tid >> 7, jj = tid & 127;
    const int h = jj >> 5, j = jj & 31;
    const void* wsrc = sp.p[2 + which];
    const int base = h * 4096 + j;
    float a = 0.f;
    if (isb) {
      const uint16_t* w16 = (const uint16_t*)wsrc;
      #pragma unroll 8
      for (int d = 0; d < 128; ++d)
        a += r[d] * b2f(w16[base + d * 32]);
    } else {
      const float* w32 = (const float*)wsrc;
      #pragma unroll 8
      for (int d = 0; d < 128; ++d)
        a += r[d] * w32[base + d * 32];
    }
    float* outp = (which == 0) ? qt : (which == 1) ? kt : vt;
    outp[row * DDIM + jj] = a;
  } else if (blk < 653) {
    // ---- wb build ----
    const int idx = (blk - 226) * 384 + tid;
    if (idx < BTOTAL) {
      float v;
      if (idx < BOFF_W1T) {                       // WOT[d][c] = W_O[c*128+d]
        int l = idx, d = l >> 7, c = l & 127;
        v = ldsrc(sp.p[5], c * 128 + d, isb);
      } else if (idx < BOFF_W2T) {                // W1T[n][d] = W1[d*512+n]
        int l = idx - BOFF_W1T, n = l >> 7, d = l & 127;
        v = ldsrc(sp.p[6], d * 512 + n, isb);
      } else if (idx < BOFF_WUP) {                // W2T[d][j] = W2[j*128+d]
        int l = idx - BOFF_W2T, d = l >> 9, j = l & 511;
        v = ldsrc(sp.p[8], j * 128 + d, isb);
      } else {                                    // WUP[v][d] = W_U[v*128+d] or 0
        int l = idx - BOFF_WUP, vv = l >> 7, d = l & 127;
        v = (vv < NVOCAB) ? ldsrc(sp.p[10], vv * 128 + d, isb) : 0.f;
      }
      wb[idx] = f2b(v);
    }
  } else {
    // ---- biases ----
    const int i = (blk - 653) * 384 + tid;
    if (i < 512) wf[OFF_B1 + i] = ldsrc(sp.p[7], i, isb);
    else if (i < 640) wf[OFF_B2 + (i - 512)] = ldsrc(sp.p[9], i - 512, isb);
  }
}

// ---------------- K2: fused MFMA kernel, 16 pairs (32 rows) / block -------
// Cross-barrier weight pipeline: each GEMM's B-operands are ISSUED in the
// preceding region (before its __syncthreads), so the vmcnt drain overlaps
// the barrier + LDS A-fragment reads instead of being exposed cold.
// MFMA accumulation order identical to R4/R6 -> bit-identical output.
__global__ void __launch_bounds__(512, 2) pair_mfma_kernel(
    const float* __restrict__ resid_pre, const float* __restrict__ qt,
    const float* __restrict__ kt, const float* __restrict__ vt,
    const float* __restrict__ wf, const uint16_t* __restrict__ wb,
    float* __restrict__ table) {
  __shared__ uint16_t bufH[ROWS_PB * 512];   // 32 KB (H staging)
  __shared__ uint16_t bufZ[ROWS_PB * 128];   // 8 KB (Z, then R)
  __shared__ uint16_t bufS[ROWS_PB * 128];   // 8 KB (smid bf16)
  __shared__ float    spat[PAIRS_PB * 16];

  const int tid = threadIdx.x;
  const int blk = blockIdx.x;
  const int lane = tid & 63;
  const int npar = tid >> 6;            // wave id 0..7
  const int l15 = lane & 15, quad = lane >> 4;

  #define ROW_OF(row_) ({                                        \
    int pr_ = blk * PAIRS_PB + ((row_) >> 1);                    \
    if (pr_ >= NPAIR) pr_ = NPAIR - 1;                           \
    int t0_ = pr_ / NVOCAB, t1_ = pr_ - t0_ * NVOCAB;            \
    ((row_) & 1) ? t1_ * 2 + 1 : t0_ * 2; })

  // ---- top-of-kernel prefetches (ride the prologue latency) ----
  const int nG = npar * 16 + l15;       // N=128 column for GEMM0/2/3

  // GEMM0 B-operands issued at the very top
  short8 bW0[4];
  {
    const uint16_t* bp = wb + BOFF_WOT + nG * 128 + quad * 8;
    #pragma unroll
    for (int ks = 0; ks < 4; ++ks) bW0[ks] = *(const short8*)(bp + ks * 32);
  }

  float rpre[2][4];
  #pragma unroll
  for (int mf = 0; mf < 2; ++mf)
    #pragma unroll
    for (int r = 0; r < 4; ++r)
      rpre[mf][r] = resid_pre[ROW_OF(mf * 16 + quad * 4 + r) * DDIM + nG];
  float bias1v[4];
  #pragma unroll
  for (int ni = 0; ni < 4; ++ni)
    bias1v[ni] = wf[OFF_B1 + (npar + ni * 8) * 16 + l15];
  const float bias2 = wf[OFF_B2 + nG];
  // vt rows for the Z phase: 2 rows x 8 cols
  const int zm = tid >> 4, zc0 = (tid & 15) * 8;
  float4 zv0a, zv0b, zv1a, zv1b;
  {
    const int zr0 = ROW_OF((zm >> 1) * 2);
    const int zr1 = ROW_OF((zm >> 1) * 2 + 1);
    const float4* p0 = (const float4*)(vt + zr0 * DDIM + zc0);
    const float4* p1 = (const float4*)(vt + zr1 * DDIM + zc0);
    zv0a = p0[0]; zv0b = p0[1]; zv1a = p1[0]; zv1b = p1[1];
  }

  // ---- prologue: scores (16 pairs x 16 scores = 256 threads) ----
  if (tid < 256) {
    const int pl = tid >> 4, s = tid & 15;
    const int pair = blk * PAIRS_PB + pl;
    if (pair < NPAIR) {
      const int t0 = pair / NVOCAB, t1 = pair - t0 * NVOCAB;
      const int row0 = t0 * 2, row1 = t1 * 2 + 1;
      const int h = s >> 2, qp = (s >> 1) & 1, spp = s & 1;
      const float4* qrow = (const float4*)(qt + (qp ? row1 : row0) * DDIM + h * 32);
      const float4* krow = (const float4*)(kt + (spp ? row1 : row0) * DDIM + h * 32);
      float acc = 0.f;
      #pragma unroll
      for (int j = 0; j < 8; ++j) {
        float4 qv = qrow[j], kv = krow[j];
        acc += qv.x * kv.x + qv.y * kv.y + qv.z * kv.z + qv.w * kv.w;
      }
      spat[pl * 16 + s] = acc * 0.17677669529663687f;
    } else {
      spat[pl * 16 + s] = 0.f;
    }
  }
  __syncthreads();

  // ---- softmax + blend ----
  if (tid < 128) {
    const int pl = tid >> 3, s = tid & 7;
    const int base = pl * 16 + s * 2;
    float s0 = spat[base], s1 = spat[base + 1];
    float m = fmaxf(s0, s1);
    float e0 = __expf(s0 - m), e1 = __expf(s1 - m);
    float inv = 1.f / (e0 + e1);
    spat[base]     = 0.5f + 0.5f * e0 * inv;
    spat[base + 1] = 0.5f + 0.5f * e1 * inv;
  }
  __syncthreads();

  // ---- Z = pattern-weighted V (prefetched), staged bf16 ----
  {
    const int pl = zm >> 1, qp = zm & 1;
    const int h = zc0 >> 5;
    const float p0 = spat[pl * 16 + h * 4 + qp * 2];
    const float p1 = spat[pl * 16 + h * 4 + qp * 2 + 1];
    float v0[8] = {zv0a.x, zv0a.y, zv0a.z, zv0a.w, zv0b.x, zv0b.y, zv0b.z, zv0b.w};
    float v1[8] = {zv1a.x, zv1a.y, zv1a.z, zv1a.w, zv1b.x, zv1b.y, zv1b.z, zv1b.w};
    short8 pk;
    #pragma unroll
    for (int e = 0; e < 8; ++e)
      pk[e] = (short)f2b(p0 * v0[e] + p1 * v1[e]);
    *(short8*)&bufZ[(zm * 16 + ((zc0 >> 3) ^ (zm & 15))) * 8] = pk;
  }
  __syncthreads();

  float smid[2][4];
  short8 bW1a[2][4];                     // GEMM1 half0 weights (cross-barrier)

  // ---- GEMM0: smid = Z x WOT + resid  (N=128, K=128) ----
  {
    short8 af[2][4];
    #pragma unroll
    for (int mf = 0; mf < 2; ++mf)
      #pragma unroll
      for (int ks = 0; ks < 4; ++ks)
        af[mf][ks] = *(const short8*)&bufZ[((mf * 16 + l15) * 16 +
                                           ((ks * 4 + quad) ^ l15)) * 8];
    float4v acc[2] = {{0.f, 0.f, 0.f, 0.f}, {0.f, 0.f, 0.f, 0.f}};
    #pragma unroll
    for (int mf = 0; mf < 2; ++mf)
      #pragma unroll
      for (int ks = 0; ks < 4; ++ks)
        acc[mf] = __builtin_amdgcn_mfma_f32_16x16x32_bf16(af[mf][ks], bW0[ks],
                                                          acc[mf], 0, 0, 0);
    // issue GEMM1 half0 B-loads BEFORE the stores + barrier
    #pragma unroll
    for (int nj = 0; nj < 2; ++nj) {
      const int n = (npar + nj * 8) * 16 + l15;
      const uint16_t* bp = wb + BOFF_W1T + n * 128 + quad * 8;
      #pragma unroll
      for (int ks = 0; ks < 4; ++ks)
        bW1a[nj][ks] = *(const short8*)(bp + ks * 32);
    }
    #pragma unroll
    for (int mf = 0; mf < 2; ++mf)
      #pragma unroll
      for (int r = 0; r < 4; ++r) {
        const int row = mf * 16 + quad * 4 + r;
        float v = acc[mf][r] + rpre[mf][r];
        smid[mf][r] = v;
        bufS[(row * 16 + ((nG >> 3) ^ (row & 15))) * 8 + (nG & 7)] = f2b(v);
      }
  }
  __syncthreads();

  short8 bB2a[8];                        // GEMM2 half0 weights (cross-barrier)

  // ---- GEMM1: H = relu(smid x W1 + b1)  (N=512, K=128) ----
  {
    short8 af[2][4];
    #pragma unroll
    for (int mf = 0; mf < 2; ++mf)
      #pragma unroll
      for (int ks = 0; ks < 4; ++ks)
        af[mf][ks] = *(const short8*)&bufS[((mf * 16 + l15) * 16 +
                                           ((ks * 4 + quad) ^ l15)) * 8];
    // half 0: ni = 0,1 (weights already in flight)
    #pragma unroll
    for (int nj = 0; nj < 2; ++nj) {
      const int ni = nj;
      const int n = (npar + ni * 8) * 16 + l15;
      float4v acc[2] = {{0.f, 0.f, 0.f, 0.f}, {0.f, 0.f, 0.f, 0.f}};
      #pragma unroll
      for (int mf = 0; mf < 2; ++mf)
        #pragma unroll
        for (int ks = 0; ks < 4; ++ks)
          acc[mf] = __builtin_amdgcn_mfma_f32_16x16x32_bf16(
              af[mf][ks], bW1a[nj][ks], acc[mf], 0, 0, 0);
      const float bias = bias1v[ni];
      #pragma unroll
      for (int mf = 0; mf < 2; ++mf)
        #pragma unroll
        for (int r = 0; r < 4; ++r) {
          const int row = mf * 16 + quad * 4 + r;
          bufH[(row * 64 + ((n >> 3) ^ (row & 15))) * 8 + (n & 7)] =
              f2b(fmaxf(acc[mf][r] + bias, 0.f));
        }
    }
    // half 1: ni = 2,3 — issue loads, compute
    short8 bW1b[2][4];
    #pragma unroll
    for (int nj = 0; nj < 2; ++nj) {
      const int n = (npar + (2 + nj) * 8) * 16 + l15;
      const uint16_t* bp = wb + BOFF_W1T + n * 128 + quad * 8;
      #pragma unroll
      for (int ks = 0; ks < 4; ++ks)
        bW1b[nj][ks] = *(const short8*)(bp + ks * 32);
    }
    #pragma unroll
    for (int nj = 0; nj < 2; ++nj) {
      const int ni = 2 + nj;
      const int n = (npar + ni * 8) * 16 + l15;
      float4v acc[2] = {{0.f, 0.f, 0.f, 0.f}, {0.f, 0.f, 0.f, 0.f}};
      #pragma unroll
      for (int mf = 0; mf < 2; ++mf)
        #pragma unroll
        for (int ks = 0; ks < 4; ++ks)
          acc[mf] = __builtin_amdgcn_mfma_f32_16x16x32_bf16(
              af[mf][ks], bW1b[nj][ks], acc[mf], 0, 0, 0);
      const float bias = bias1v[ni];
      #pragma unroll
      for (int mf = 0; mf < 2; ++mf)
        #pragma unroll
        for (int r = 0; r < 4; ++r) {
          const int row = mf * 16 + quad * 4 + r;
          bufH[(row * 64 + ((n >> 3) ^ (row & 15))) * 8 + (n & 7)] =
              f2b(fmaxf(acc[mf][r] + bias, 0.f));
        }
    }
    // issue GEMM2 half0 B-loads BEFORE the barrier
    {
      const uint16_t* bp = wb + BOFF_W2T + nG * 512 + quad * 8;
      #pragma unroll
      for (int k8 = 0; k8 < 8; ++k8)
        bB2a[k8] = *(const short8*)(bp + k8 * 32);
    }
  }
  __syncthreads();

  short8 bW3[4];                         // GEMM3 weights (cross-barrier)

  // ---- GEMM2: R = smid + H x W2 + b2  (N=128, K=512) ----
  {
    const uint16_t* bp = wb + BOFF_W2T + nG * 512 + quad * 8;
    float4v acc0 = {0.f, 0.f, 0.f, 0.f};
    float4v acc1 = {0.f, 0.f, 0.f, 0.f};
    // half 0 (k = 0..7), weights already in flight
    #pragma unroll
    for (int qtr = 0; qtr < 2; ++qtr) {
      short8 a0[4], a1[4];
      #pragma unroll
      for (int k4 = 0; k4 < 4; ++k4) {
        const int ks = qtr * 4 + k4;
        a0[k4] = *(const short8*)&bufH[(l15 * 64 + ((ks * 4 + quad) ^ l15)) * 8];
        a1[k4] = *(const short8*)&bufH[((16 + l15) * 64 +
                                       ((ks * 4 + quad) ^ l15)) * 8];
      }
      #pragma unroll
      for (int k4 = 0; k4 < 4; ++k4) {
        acc0 = __builtin_amdgcn_mfma_f32_16x16x32_bf16(
            a0[k4], bB2a[qtr * 4 + k4], acc0, 0, 0, 0);
        acc1 = __builtin_amdgcn_mfma_f32_16x16x32_bf16(
            a1[k4], bB2a[qtr * 4 + k4], acc1, 0, 0, 0);
      }
    }
    // half 1 (k = 8..15): issue loads, compute
    short8 bB2b[8];
    #pragma unroll
    for (int k8 = 0; k8 < 8; ++k8)
      bB2b[k8] = *(const short8*)(bp + (8 + k8) * 32);
    #pragma unroll
    for (int qtr = 0; qtr < 2; ++qtr) {
      short8 a0[4], a1[4];
      #pragma unroll
      for (int k4 = 0; k4 < 4; ++k4) {
        const int ks = 8 + qtr * 4 + k4;
        a0[k4] = *(const short8*)&bufH[(l15 * 64 + ((ks * 4 + quad) ^ l15)) * 8];
        a1[k4] = *(const short8*)&bufH[((16 + l15) * 64 +
                                       ((ks * 4 + quad) ^ l15)) * 8];
      }
      #pragma unroll
      for (int k4 = 0; k4 < 4; ++k4) {
        acc0 = __builtin_amdgcn_mfma_f32_16x16x32_bf16(
            a0[k4], bB2b[qtr * 4 + k4], acc0, 0, 0, 0);
        acc1 = __builtin_amdgcn_mfma_f32_16x16x32_bf16(
            a1[k4], bB2b[qtr * 4 + k4], acc1, 0, 0, 0);
      }
    }
    // issue GEMM3 B-loads BEFORE the stores + barrier
    {
      const uint16_t* bp3 = wb + BOFF_WUP + nG * 128 + quad * 8;
      #pragma unroll
      for (int ks = 0; ks < 4; ++ks)
        bW3[ks] = *(const short8*)(bp3 + ks * 32);
    }
    #pragma unroll
    for (int r = 0; r < 4; ++r) {
      const int row0 = quad * 4 + r;
      const int row1 = 16 + quad * 4 + r;
      bufZ[(row0 * 16 + ((nG >> 3) ^ (row0 & 15))) * 8 + (nG & 7)] =
          f2b(acc0[r] + bias2 + smid[0][r]);
      bufZ[(row1 * 16 + ((nG >> 3) ^ (row1 & 15))) * 8 + (nG & 7)] =
          f2b(acc1[r] + bias2 + smid[1][r]);
    }
  }
  __syncthreads();

  // ---- GEMM3: logits = R x WUP^T -> DENSE table store (L2-resident) ----
  {
    short8 ar[2][4];
    #pragma unroll
    for (int mf = 0; mf < 2; ++mf)
      #pragma unroll
      for (int ks = 0; ks < 4; ++ks)
        ar[mf][ks] = *(const short8*)&bufZ[((mf * 16 + l15) * 16 +
                                           ((ks * 4 + quad) ^ l15)) * 8];
    float4v acc[2] = {{0.f, 0.f, 0.f, 0.f}, {0.f, 0.f, 0.f, 0.f}};
    #pragma unroll
    for (int mf = 0; mf < 2; ++mf)
      #pragma unroll
      for (int ks = 0; ks < 4; ++ks)
        acc[mf] = __builtin_amdgcn_mfma_f32_16x16x32_bf16(ar[mf][ks], bW3[ks],
                                                          acc[mf], 0, 0, 0);
    if (nG < NVOCAB) {
      #pragma unroll
      for (int mf = 0; mf < 2; ++mf)
        #pragma unroll
        for (int r = 0; r < 4; ++r) {
          const int row = mf * 16 + quad * 4 + r;
          const int pair = blk * PAIRS_PB + (row >> 1);
          if (pair < NPAIR)
            table[pair * 226 + (row & 1) * 113 + nG] = acc[mf][r];
        }
    }
  }
  #undef ROW_OF
}

// ---------------- K3: gather — random L2 table reads, DENSE out writes -----
__global__ void gather_kernel(const uint32_t* __restrict__ x_raw,
                              const f2v* __restrict__ table2,
                              f2v* __restrict__ out2, int total) {
  // per-wave int64 self-detect: int64 tokens -> odd u32s (high words) all 0
  uint32_t xs = x_raw[2 * (threadIdx.x & 63) + 1];
  unsigned long long nz = __ballot(xs != 0u);
  const int is64 = (nz == 0ull);

  const int i = blockIdx.x * 256 + threadIdx.x;
  if (i >= total) return;
  const int b = i / NVOCAB;
  const int j = i - b * NVOCAB;
  int t0, t1;
  if (is64) {
    t0 = (int)x_raw[4 * b];
    t1 = (int)x_raw[4 * b + 2];
  } else {
    t0 = (int)x_raw[2 * b];
    t1 = (int)x_raw[2 * b + 1];
  }
  t0 = min(max(t0, 0), NVOCAB - 1);
  t1 = min(max(t1, 0), NVOCAB - 1);
  const int pair = t0 * NVOCAB + t1;
  f2v v = table2[(size_t)pair * NVOCAB + j];
  __builtin_nontemporal_store(v, &out2[i]);
}

extern "C" void kernel_launch(void* const* d_in, const int* in_sizes, int n_in,
                              void* d_out, int out_size, void* d_ws, size_t ws_size,
                              hipStream_t stream) {
  // ws layout (byte offsets)
  float*    wf        = (float*)((char*)d_ws + 256);             // biases only
  float*    resid_pre = (float*)((char*)d_ws + 905984);
  float*    qt        = (float*)((char*)d_ws + 1021696);
  float*    kt        = (float*)((char*)d_ws + 1137408);
  float*    vt        = (float*)((char*)d_ws + 1253120);
  float*    table     = (float*)((char*)d_ws + 1368832);         // 11543176 B
  uint16_t* wb        = (uint16_t*)((char*)d_ws + 12912016);     // 327680 B

  const int B = in_sizes[0] / 2;

  SrcPtrs sp;
  for (int i = 0; i < 11; ++i) sp.p[i] = d_in[i + 1];

  // 226 qkv + 427 wb + 2 bias = 655 blocks
  build_kernel<<<655, 384, 0, stream>>>(sp, wf, resid_pre, qt, kt, vt, wb);

  const int nblk = (NPAIR + PAIRS_PB - 1) / PAIRS_PB;  // 799
  pair_mfma_kernel<<<nblk, 512, 0, stream>>>(resid_pre, qt, kt, vt, wf, wb,
                                             table);

  const int total = B * NVOCAB;   // float2 elements of out
  gather_kernel<<<(total + 255) / 256, 256, 0, stream>>>(
      (const uint32_t*)d_in[0], (const f2v*)table, (f2v*)d_out, total);
}